// Round 2
// baseline (188.655 us; speedup 1.0000x reference)
//
#include <hip/hip_runtime.h>

typedef unsigned short u16;
typedef __attribute__((ext_vector_type(8))) short s16x8;
typedef __attribute__((ext_vector_type(4))) float f32x4;

#define MFMA16(a, b, c) __builtin_amdgcn_mfma_f32_16x16x32_bf16((a), (b), (c), 0, 0, 0)

// round-to-nearest-even f32 -> bf16 (as raw u16)
__device__ __forceinline__ u16 f2bf(float f) {
  unsigned u = __float_as_uint(f);
  u += 0x7fffu + ((u >> 16) & 1u);
  return (u16)(u >> 16);
}
__device__ __forceinline__ float bf2f(u16 h) { return __uint_as_float(((unsigned)h) << 16); }

// async global->LDS, 16B per lane, wave-uniform LDS base (+lane*16 by HW)
__device__ __forceinline__ void gld_lds16(const void* g, void* l) {
  __builtin_amdgcn_global_load_lds(
      (const __attribute__((address_space(1))) void*)g,
      (__attribute__((address_space(3))) void*)l, 16, 0, 0);
}

// ---------------------------------------------------------------------------
// split X f32 -> Xh, Xl bf16 (same [8192][512] layout). 8 elems/thread.
// ---------------------------------------------------------------------------
__global__ __launch_bounds__(256) void xsplit(const float* __restrict__ X,
                                              u16* __restrict__ Xh, u16* __restrict__ Xl) {
  size_t idx = (size_t)blockIdx.x * 256 + threadIdx.x;
  const float4 f0 = *(const float4*)(X + idx * 8);
  const float4 f1 = *(const float4*)(X + idx * 8 + 4);
  float fs[8] = {f0.x, f0.y, f0.z, f0.w, f1.x, f1.y, f1.z, f1.w};
  s16x8 hv, lv;
#pragma unroll
  for (int j = 0; j < 8; ++j) {
    u16 h = f2bf(fs[j]);
    hv[j] = (short)h;
    lv[j] = (short)f2bf(fs[j] - bf2f(h));
  }
  *(s16x8*)(Xh + idx * 8) = hv;
  *(s16x8*)(Xl + idx * 8) = lv;
}

// ---------------------------------------------------------------------------
// transpose + split weights: W[K][N] f32 -> T{h,l}[N][K] bf16
// ---------------------------------------------------------------------------
__global__ __launch_bounds__(256) void wsplit_T(const float* __restrict__ W, int K, int N,
                                                u16* __restrict__ Th, u16* __restrict__ Tl) {
  int idx = blockIdx.x * 256 + threadIdx.x;
  int total = N * (K >> 3);
  if (idx >= total) return;
  int n = idx % N;
  int kc = idx / N;
  size_t ob = (size_t)n * K + (size_t)kc * 8;
  for (int i = 0; i < 8; ++i) {
    float f = W[(size_t)(kc * 8 + i) * N + n];
    u16 h = f2bf(f);
    Th[ob + i] = h;
    Tl[ob + i] = f2bf(f - bf2f(h));
  }
}

// ---------------------------------------------------------------------------
// Shared 128x128 bf16x2 (3-term) GEMM template, BK=32, double-buffered,
// global_load_lds staging with pre-swizzled source + swizzled ds_read.
// A{h,l}[M][512], B{h,l}[N][512] row-major (K contiguous).
// EPI=1: qkv scatter epilogue (gemm1).  EPI=0: plain f32 store (gemm2).
// ---------------------------------------------------------------------------
template <int EPI>
__global__ __launch_bounds__(256, 2) void gemm_bf16x2(
    const u16* __restrict__ Aht, const u16* __restrict__ Alt,
    const u16* __restrict__ Bht, const u16* __restrict__ Blt,
    float* __restrict__ OUT,
    u16* __restrict__ qh, u16* __restrict__ ql,
    u16* __restrict__ kh, u16* __restrict__ kl,
    u16* __restrict__ vth, u16* __restrict__ vtl) {
  __shared__ u16 Ah[2][128][32], Al[2][128][32], Bh[2][128][32], Bl[2][128][32];
  const int tid = threadIdx.x;
  const int w = tid >> 6, lane = tid & 63;
  const int l15 = lane & 15, l4 = lane >> 4;
  const int row0 = blockIdx.x * 128;
  const int col0 = blockIdx.y * 128;
  const int wr = w >> 1, wc = w & 1;  // wave 2x2, each 64x64

  // per-lane swizzled global source offsets (bytes):
  // lane -> LDS (row=lane>>2, slot=lane&3); source slot = slot ^ (row&3)
  const int lr = lane >> 2, lc = lane & 3;
  const int swz = ((lc ^ (lr & 3)) << 3);  // element offset within row
  const size_t offA = ((size_t)(row0 + w * 32 + lr) * 512 + swz) * 2;
  const size_t offB = ((size_t)(col0 + w * 32 + lr) * 512 + swz) * 2;
  const char* pAh = (const char*)Aht + offA;
  const char* pAl = (const char*)Alt + offA;
  const char* pBh = (const char*)Bht + offB;
  const char* pBl = (const char*)Blt + offB;

#define STAGE(t_, b_)                                          \
  do {                                                         \
    const size_t kb = (size_t)(t_) * 64;                       \
    gld_lds16(pAh + kb,         &Ah[b_][w * 32][0]);           \
    gld_lds16(pAh + kb + 16384, &Ah[b_][w * 32 + 16][0]);      \
    gld_lds16(pAl + kb,         &Al[b_][w * 32][0]);           \
    gld_lds16(pAl + kb + 16384, &Al[b_][w * 32 + 16][0]);      \
    gld_lds16(pBh + kb,         &Bh[b_][w * 32][0]);           \
    gld_lds16(pBh + kb + 16384, &Bh[b_][w * 32 + 16][0]);      \
    gld_lds16(pBl + kb,         &Bl[b_][w * 32][0]);           \
    gld_lds16(pBl + kb + 16384, &Bl[b_][w * 32 + 16][0]);      \
  } while (0)

  const f32x4 fz = {0.f, 0.f, 0.f, 0.f};
  f32x4 acc[4][4];
  for (int a = 0; a < 4; ++a)
    for (int b = 0; b < 4; ++b) acc[a][b] = fz;

  STAGE(0, 0);
  __syncthreads();  // drains vmcnt -> buf0 ready

  for (int t = 0; t < 16; ++t) {
    const int c = t & 1;
    if (t + 1 < 16) STAGE(t + 1, c ^ 1);
    s16x8 afh[4], afl[4];
#pragma unroll
    for (int mi = 0; mi < 4; ++mi) {
      const int r = wr * 64 + mi * 16 + l15;
      const int sl = (l4 ^ (r & 3)) << 3;
      afh[mi] = *(const s16x8*)&Ah[c][r][sl];
      afl[mi] = *(const s16x8*)&Al[c][r][sl];
    }
#pragma unroll
    for (int nj = 0; nj < 4; ++nj) {
      const int r = wc * 64 + nj * 16 + l15;
      const int sl = (l4 ^ (r & 3)) << 3;
      const s16x8 bfh = *(const s16x8*)&Bh[c][r][sl];
      const s16x8 bfl = *(const s16x8*)&Bl[c][r][sl];
#pragma unroll
      for (int mi = 0; mi < 4; ++mi) {
        acc[mi][nj] = MFMA16(afh[mi], bfh, acc[mi][nj]);
        acc[mi][nj] = MFMA16(afl[mi], bfh, acc[mi][nj]);
        acc[mi][nj] = MFMA16(afh[mi], bfl, acc[mi][nj]);
      }
    }
    __syncthreads();  // drains vmcnt(0)+lgkmcnt(0): next buf staged, cur reads done
  }
#undef STAGE

  if (EPI == 1) {
    // scatter to q (scaled), k, vT as bf16 hi/lo
    const float QS = 0.06375874f;  // D^-0.5 * log2(e)
#pragma unroll
    for (int mi = 0; mi < 4; ++mi)
#pragma unroll
      for (int nj = 0; nj < 4; ++nj)
#pragma unroll
        for (int rg = 0; rg < 4; ++rg) {
          float v = acc[mi][nj][rg];
          int r_g = row0 + wr * 64 + mi * 16 + l4 * 4 + rg;
          int c_g = col0 + wc * 64 + nj * 16 + l15;
          int b = r_g >> 11, s = r_g & 2047;
          int h = c_g / 192;
          int rem = c_g - h * 192;
          int t = rem >> 6, d = rem & 63;
          int bh_ = b * 8 + h;
          if (t == 0) {
            v *= QS;
            u16 hi = f2bf(v), lo = f2bf(v - bf2f(hi));
            size_t o = ((size_t)bh_ * 2048 + s) * 64 + d;
            qh[o] = hi; ql[o] = lo;
          } else if (t == 1) {
            u16 hi = f2bf(v), lo = f2bf(v - bf2f(hi));
            size_t o = ((size_t)bh_ * 2048 + s) * 64 + d;
            kh[o] = hi; kl[o] = lo;
          } else {
            u16 hi = f2bf(v), lo = f2bf(v - bf2f(hi));
            size_t o = ((size_t)bh_ * 64 + d) * 2048 + s;
            vth[o] = hi; vtl[o] = lo;
          }
        }
  } else {
#pragma unroll
    for (int mi = 0; mi < 4; ++mi)
#pragma unroll
      for (int nj = 0; nj < 4; ++nj)
#pragma unroll
        for (int rg = 0; rg < 4; ++rg) {
          int r_g = row0 + wr * 64 + mi * 16 + l4 * 4 + rg;
          int c_g = col0 + wc * 64 + nj * 16 + l15;
          OUT[(size_t)r_g * 512 + c_g] = acc[mi][nj][rg];
        }
  }
}

// ---------------------------------------------------------------------------
// Banded flash attention. Block = (b, h, qtile of 128). 4 waves x 32 q-rows.
// Scores already in log2-domain (q pre-scaled). Mask |i-j|>128 -> -1e9.
// ---------------------------------------------------------------------------
__global__ __launch_bounds__(256) void attn_kernel(
    const u16* __restrict__ qh, const u16* __restrict__ ql,
    const u16* __restrict__ kh, const u16* __restrict__ kl,
    const u16* __restrict__ vth, const u16* __restrict__ vtl,
    u16* __restrict__ aoh, u16* __restrict__ aol) {
  __shared__ u16 Ph[4][32][64], Pl[4][32][64];
  const int tid = threadIdx.x;
  const int w = tid >> 6, lane = tid & 63;
  const int l15 = lane & 15, l4 = lane >> 4;
  int bid = blockIdx.x;
  int qt = bid & 15, hh = (bid >> 4) & 7, b = bid >> 7;
  int bh_ = b * 8 + hh;
  const size_t base = (size_t)bh_ * 2048 * 64;
  int q0 = qt * 128 + w * 32;

  s16x8 qfh[2][2], qfl[2][2];
#pragma unroll
  for (int mi = 0; mi < 2; ++mi)
#pragma unroll
    for (int ks = 0; ks < 2; ++ks) {
      size_t o = base + (size_t)(q0 + mi * 16 + l15) * 64 + ks * 32 + l4 * 8;
      qfh[mi][ks] = *(const s16x8*)(qh + o);
      qfl[mi][ks] = *(const s16x8*)(ql + o);
    }

  const f32x4 fz = {0.f, 0.f, 0.f, 0.f};
  f32x4 O[2][4];
  for (int mi = 0; mi < 2; ++mi)
    for (int nd = 0; nd < 4; ++nd) O[mi][nd] = fz;
  float m_r[2][4], l_r[2][4];
  for (int mi = 0; mi < 2; ++mi)
    for (int rg = 0; rg < 4; ++rg) { m_r[mi][rg] = -3.0e38f; l_r[mi][rg] = 0.f; }

  for (int dt = -1; dt <= 1; ++dt) {
    int kt = qt + dt;
    if (kt < 0 || kt > 15) continue;
    const bool domask = (dt != 0);
    for (int ch = 0; ch < 2; ++ch) {
      int kb = kt * 128 + ch * 64;
      f32x4 S[2][4];
      for (int mi = 0; mi < 2; ++mi)
        for (int nj = 0; nj < 4; ++nj) S[mi][nj] = fz;
#pragma unroll
      for (int nj = 0; nj < 4; ++nj)
#pragma unroll
        for (int ks = 0; ks < 2; ++ks) {
          size_t o = base + (size_t)(kb + nj * 16 + l15) * 64 + ks * 32 + l4 * 8;
          s16x8 kfh = *(const s16x8*)(kh + o);
          s16x8 kfl = *(const s16x8*)(kl + o);
#pragma unroll
          for (int mi = 0; mi < 2; ++mi) {
            S[mi][nj] = MFMA16(qfh[mi][ks], kfh, S[mi][nj]);
            S[mi][nj] = MFMA16(qfl[mi][ks], kfh, S[mi][nj]);
            S[mi][nj] = MFMA16(qfh[mi][ks], kfl, S[mi][nj]);
          }
        }
      if (domask) {
#pragma unroll
        for (int mi = 0; mi < 2; ++mi)
#pragma unroll
          for (int nj = 0; nj < 4; ++nj)
#pragma unroll
            for (int rg = 0; rg < 4; ++rg) {
              int row = q0 + mi * 16 + l4 * 4 + rg;
              int col = kb + nj * 16 + l15;
              int dd = col - row;
              if (dd > 128 || dd < -128) S[mi][nj][rg] = -1.0e9f;
            }
      }
#pragma unroll
      for (int mi = 0; mi < 2; ++mi)
#pragma unroll
        for (int rg = 0; rg < 4; ++rg) {
          float pm = fmaxf(fmaxf(S[mi][0][rg], S[mi][1][rg]), fmaxf(S[mi][2][rg], S[mi][3][rg]));
          pm = fmaxf(pm, __shfl_xor(pm, 1));
          pm = fmaxf(pm, __shfl_xor(pm, 2));
          pm = fmaxf(pm, __shfl_xor(pm, 4));
          pm = fmaxf(pm, __shfl_xor(pm, 8));
          float mnew = fmaxf(m_r[mi][rg], pm);
          float alpha = exp2f(m_r[mi][rg] - mnew);
          m_r[mi][rg] = mnew;
          l_r[mi][rg] *= alpha;
#pragma unroll
          for (int nd = 0; nd < 4; ++nd) O[mi][nd][rg] *= alpha;
        }
#pragma unroll
      for (int mi = 0; mi < 2; ++mi) {
        float rs[4] = {0.f, 0.f, 0.f, 0.f};
#pragma unroll
        for (int nj = 0; nj < 4; ++nj)
#pragma unroll
          for (int rg = 0; rg < 4; ++rg) {
            float p = exp2f(S[mi][nj][rg] - m_r[mi][rg]);
            rs[rg] += p;
            u16 hi = f2bf(p), lo = f2bf(p - bf2f(hi));
            int row = mi * 16 + l4 * 4 + rg;
            int col = nj * 16 + l15;
            int e = (((col >> 3) ^ (row & 7)) << 3) + (col & 7);
            Ph[w][row][e] = hi;
            Pl[w][row][e] = lo;
          }
#pragma unroll
        for (int rg = 0; rg < 4; ++rg) {
          float s = rs[rg];
          s += __shfl_xor(s, 1);
          s += __shfl_xor(s, 2);
          s += __shfl_xor(s, 4);
          s += __shfl_xor(s, 8);
          l_r[mi][rg] += s;
        }
      }
#pragma unroll
      for (int ksp = 0; ksp < 2; ++ksp) {
        s16x8 pah[2], pal[2];
#pragma unroll
        for (int mi = 0; mi < 2; ++mi) {
          int row = mi * 16 + l15;
          int sl = (ksp * 4 + l4) ^ (row & 7);
          pah[mi] = *(const s16x8*)&Ph[w][row][sl * 8];
          pal[mi] = *(const s16x8*)&Pl[w][row][sl * 8];
        }
#pragma unroll
        for (int nd = 0; nd < 4; ++nd) {
          size_t o = base + (size_t)(nd * 16 + l15) * 2048 + kb + ksp * 32 + l4 * 8;
          s16x8 vh = *(const s16x8*)(vth + o);
          s16x8 vl = *(const s16x8*)(vtl + o);
#pragma unroll
          for (int mi = 0; mi < 2; ++mi) {
            O[mi][nd] = MFMA16(pah[mi], vh, O[mi][nd]);
            O[mi][nd] = MFMA16(pal[mi], vh, O[mi][nd]);
            O[mi][nd] = MFMA16(pah[mi], vl, O[mi][nd]);
          }
        }
      }
    }
  }
#pragma unroll
  for (int mi = 0; mi < 2; ++mi)
#pragma unroll
    for (int rg = 0; rg < 4; ++rg) {
      float inv = 1.0f / l_r[mi][rg];
      int s_g = q0 + mi * 16 + l4 * 4 + rg;
#pragma unroll
      for (int nd = 0; nd < 4; ++nd) {
        float v = O[mi][nd][rg] * inv;
        int c_g = hh * 64 + nd * 16 + l15;
        size_t o = ((size_t)b * 2048 + s_g) * 512 + c_g;
        u16 hi = f2bf(v), lo = f2bf(v - bf2f(hi));
        aoh[o] = hi;
        aol[o] = lo;
      }
    }
}

// ---------------------------------------------------------------------------
extern "C" void kernel_launch(void* const* d_in, const int* in_sizes, int n_in,
                              void* d_out, int out_size, void* d_ws, size_t ws_size,
                              hipStream_t stream) {
  const float* x = (const float*)d_in[0];      // [4,2048,512]
  const float* wqkv = (const float*)d_in[1];   // [512,1536]
  const float* wproj = (const float*)d_in[2];  // [512,512]
  float* out = (float*)d_out;                  // [4,2048,512]

  char* ws = (char*)d_ws;
  size_t off = 0;
  auto alloc = [&](size_t bytes) {
    void* p = ws + off;
    off += (bytes + 255) & ~(size_t)255;
    return p;
  };
  const size_t E = (size_t)4 * 8 * 2048 * 64;  // 4.19M elems per tensor
  u16* qh  = (u16*)alloc(E * 2);
  u16* ql  = (u16*)alloc(E * 2);
  u16* kh  = (u16*)alloc(E * 2);
  u16* kl  = (u16*)alloc(E * 2);
  u16* vth = (u16*)alloc(E * 2);
  u16* vtl = (u16*)alloc(E * 2);
  u16* aoh = (u16*)alloc(E * 2);   // also aliased as Xh (gemm1 input, dead before attn writes)
  u16* aol = (u16*)alloc(E * 2);   // aliased as Xl
  u16* wqTh = (u16*)alloc((size_t)1536 * 512 * 2);
  u16* wqTl = (u16*)alloc((size_t)1536 * 512 * 2);
  u16* wpTh = (u16*)alloc((size_t)512 * 512 * 2);
  u16* wpTl = (u16*)alloc((size_t)512 * 512 * 2);
  u16* Xh = aoh;
  u16* Xl = aol;

  xsplit<<<dim3(2048), dim3(256), 0, stream>>>(x, Xh, Xl);
  wsplit_T<<<dim3((1536 * 64 + 255) / 256), dim3(256), 0, stream>>>(wqkv, 512, 1536, wqTh, wqTl);
  wsplit_T<<<dim3((512 * 64 + 255) / 256), dim3(256), 0, stream>>>(wproj, 512, 512, wpTh, wpTl);
  gemm_bf16x2<1><<<dim3(64, 12), dim3(256), 0, stream>>>(Xh, Xl, wqTh, wqTl, nullptr,
                                                         qh, ql, kh, kl, vth, vtl);
  attn_kernel<<<dim3(512), dim3(256), 0, stream>>>(qh, ql, kh, kl, vth, vtl, aoh, aol);
  gemm_bf16x2<0><<<dim3(64, 4), dim3(256), 0, stream>>>(aoh, aol, wpTh, wpTl, out,
                                                        nullptr, nullptr, nullptr, nullptr, nullptr, nullptr);
}

// Round 3
// 92.901 us; speedup vs baseline: 2.0307x; 2.0307x over previous
//
#include <hip/hip_runtime.h>

typedef unsigned short u16;
typedef __attribute__((ext_vector_type(8))) short s16x8;
typedef __attribute__((ext_vector_type(4))) float f32x4;

#define MFMA16(a, b, c) __builtin_amdgcn_mfma_f32_16x16x32_bf16((a), (b), (c), 0, 0, 0)

// round-to-nearest-even f32 -> bf16 (raw u16)
__device__ __forceinline__ u16 f2bf(float f) {
  unsigned u = __float_as_uint(f);
  u += 0x7fffu + ((u >> 16) & 1u);
  return (u16)(u >> 16);
}

// async global->LDS, 16B per lane, wave-uniform LDS base (+lane*16 by HW)
__device__ __forceinline__ void gld_lds16(const void* g, void* l) {
  __builtin_amdgcn_global_load_lds(
      (const __attribute__((address_space(1))) void*)g,
      (__attribute__((address_space(3))) void*)l, 16, 0, 0);
}

// ---------------------------------------------------------------------------
// cast X f32 -> bf16, same [8192][512] layout, 8 elems/thread
// ---------------------------------------------------------------------------
__global__ __launch_bounds__(256) void xcast(const float* __restrict__ X,
                                             u16* __restrict__ Xb) {
  size_t idx = (size_t)blockIdx.x * 256 + threadIdx.x;
  const float4 f0 = *(const float4*)(X + idx * 8);
  const float4 f1 = *(const float4*)(X + idx * 8 + 4);
  float fs[8] = {f0.x, f0.y, f0.z, f0.w, f1.x, f1.y, f1.z, f1.w};
  s16x8 hv;
#pragma unroll
  for (int j = 0; j < 8; ++j) hv[j] = (short)f2bf(fs[j]);
  *(s16x8*)(Xb + idx * 8) = hv;
}

// ---------------------------------------------------------------------------
// transpose + cast weights: W[K][N] f32 -> T[N][K] bf16.
// PERM=1 (wqkv): T row n' = source col h*192 + t*64 + d where
//   t=n'>>9 (q/k/v), ct=n'&511, h=ct>>6, d=ct&63  -> gemm1 col blocks map
//   cleanly: by 0-3 = q, 4-7 = k, 8-11 = v.
// ---------------------------------------------------------------------------
template <int PERM>
__global__ __launch_bounds__(256) void wcastT(const float* __restrict__ W, int K, int N,
                                              u16* __restrict__ T) {
  int idx = blockIdx.x * 256 + threadIdx.x;
  int total = N * (K >> 3);
  if (idx >= total) return;
  int n = idx % N;
  int kc = idx / N;
  int src_c;
  if (PERM) {
    int t = n >> 9, ct = n & 511, h = ct >> 6, d = ct & 63;
    src_c = h * 192 + t * 64 + d;
  } else {
    src_c = n;
  }
  s16x8 hv;
#pragma unroll
  for (int i = 0; i < 8; ++i) hv[i] = (short)f2bf(W[(size_t)(kc * 8 + i) * N + src_c]);
  *(s16x8*)(T + (size_t)n * K + (size_t)kc * 8) = hv;
}

// ---------------------------------------------------------------------------
// 128x128 bf16 GEMM, BK=64, single-buffered 32KB LDS (m97 structure),
// global_load_lds w=16 with 8-slot XOR involution (2-way = free).
// A[M][512], B[N][512] row-major bf16 (K contiguous).
// EPI=1 (gemm1): by 0-3 -> q (scaled by QS), 4-7 -> k, 8-11 -> v via LDS
//   transpose to vT[bh][64][2048] (coalesced 16B stores).
// EPI=0 (gemm2): f32 OUT.
// ---------------------------------------------------------------------------
template <int EPI>
__global__ __launch_bounds__(256) void gemm_bf16(
    const u16* __restrict__ A, const u16* __restrict__ B,
    float* __restrict__ OUT,
    u16* __restrict__ qo, u16* __restrict__ ko, u16* __restrict__ vto) {
  __shared__ u16 LDS[EPI ? 16640 : 16384];  // SA 16KB | SB 16KB ; v-transpose reuses
  u16* SA = LDS;
  u16* SB = LDS + 8192;
  const int tid = threadIdx.x;
  const int w = tid >> 6, lane = tid & 63;
  const int l15 = lane & 15, l4 = lane >> 4;
  const int row0 = blockIdx.x * 128;
  const int col0 = blockIdx.y * 128;
  const int wr = w >> 1, wc = w & 1;  // wave 2x2, each 64x64

  // staging: per gld, 8 rows x 128B; lane -> row lane>>3, slot (lane&7)^(row&7)
  const int lrow = lane >> 3, lslot = lane & 7;
  const int srcoff = lrow * 1024 + ((lslot ^ lrow) << 4);  // bytes
  const char* pA = (const char*)A + (size_t)(row0 + w * 32) * 1024 + srcoff;
  const char* pB = (const char*)B + (size_t)(col0 + w * 32) * 1024 + srcoff;
  u16* sAw = SA + (w * 32) * 64;
  u16* sBw = SB + (w * 32) * 64;

  const f32x4 fz = {0.f, 0.f, 0.f, 0.f};
  f32x4 acc[4][4];
  for (int a = 0; a < 4; ++a)
    for (int b = 0; b < 4; ++b) acc[a][b] = fz;

  for (int t = 0; t < 8; ++t) {
    const size_t kb = (size_t)t * 128;  // bytes along K
#pragma unroll
    for (int j = 0; j < 4; ++j) {
      gld_lds16(pA + j * 8192 + kb, sAw + j * 512);
      gld_lds16(pB + j * 8192 + kb, sBw + j * 512);
    }
    __syncthreads();  // drain vmcnt: tile ready
#pragma unroll
    for (int ks = 0; ks < 2; ++ks) {
      s16x8 af[4], bf[4];
#pragma unroll
      for (int mi = 0; mi < 4; ++mi) {
        const int r = wr * 64 + mi * 16 + l15;
        const int sl = (ks * 4 + l4) ^ (r & 7);
        af[mi] = *(const s16x8*)&SA[r * 64 + sl * 8];
      }
#pragma unroll
      for (int nj = 0; nj < 4; ++nj) {
        const int r = wc * 64 + nj * 16 + l15;
        const int sl = (ks * 4 + l4) ^ (r & 7);
        bf[nj] = *(const s16x8*)&SB[r * 64 + sl * 8];
      }
#pragma unroll
      for (int nj = 0; nj < 4; ++nj)
#pragma unroll
        for (int mi = 0; mi < 4; ++mi) acc[mi][nj] = MFMA16(af[mi], bf[nj], acc[mi][nj]);
    }
    __syncthreads();  // all reads done before next stage overwrites
  }

  if (EPI == 0) {
#pragma unroll
    for (int mi = 0; mi < 4; ++mi)
#pragma unroll
      for (int nj = 0; nj < 4; ++nj)
#pragma unroll
        for (int rg = 0; rg < 4; ++rg) {
          int r_g = row0 + wr * 64 + mi * 16 + l4 * 4 + rg;
          int c_g = col0 + wc * 64 + nj * 16 + l15;
          OUT[(size_t)r_g * 512 + c_g] = acc[mi][nj][rg];
        }
    return;
  }

  // ---- gemm1 epilogue ----
  const int by = blockIdx.y;
  const int b = row0 >> 11, srow = row0 & 2047;
  if (by < 8) {
    // q or k: [bh][s][64] bf16
    const int isq = (by < 4);
    const float QS = 0.06375874f;  // 512^-0.5 * log2(e)
    u16* dst = isq ? qo : ko;
#pragma unroll
    for (int mi = 0; mi < 4; ++mi)
#pragma unroll
      for (int nj = 0; nj < 4; ++nj)
#pragma unroll
        for (int rg = 0; rg < 4; ++rg) {
          float v = acc[mi][nj][rg];
          if (isq) v *= QS;
          int s = srow + wr * 64 + mi * 16 + l4 * 4 + rg;
          int ct = ((by & 3) * 128 + wc * 64 + nj * 16 + l15);
          int h = ct >> 6, d = ct & 63;
          dst[(((size_t)b * 8 + h) * 2048 + s) * 64 + d] = f2bf(v);
        }
  } else {
    // v: transpose via LDS (pitch 130, conflict-free) -> vT[bh][64][2048]
#pragma unroll
    for (int mi = 0; mi < 4; ++mi)
#pragma unroll
      for (int nj = 0; nj < 4; ++nj)
#pragma unroll
        for (int rg = 0; rg < 4; ++rg) {
          int c = wc * 64 + nj * 16 + l15;            // 0..127 (column)
          int s = wr * 64 + mi * 16 + l4 * 4 + rg;    // 0..127 (row)
          LDS[c * 130 + s] = f2bf(acc[mi][nj][rg]);
        }
    __syncthreads();
    const unsigned* LDSw = (const unsigned*)LDS;
    int c = tid >> 1, sh = tid & 1;
    int ct = (by - 8) * 128 + c;
    int h = ct >> 6, d = ct & 63;
    size_t o = (((size_t)b * 8 + h) * 64 + d) * 2048 + srow + sh * 64;
    unsigned wbuf[32];
#pragma unroll
    for (int p = 0; p < 32; ++p) wbuf[p] = LDSw[c * 65 + sh * 32 + p];
#pragma unroll
    for (int j = 0; j < 8; ++j) {
      uint4 u = {wbuf[j * 4], wbuf[j * 4 + 1], wbuf[j * 4 + 2], wbuf[j * 4 + 3]};
      *(uint4*)(vto + o + j * 8) = u;
    }
  }
}

// ---------------------------------------------------------------------------
// Banded flash attention, plain bf16. Block = (b, h, qtile of 128).
// 4 waves x 32 q-rows; scores in log2 domain (q pre-scaled by QS).
// ---------------------------------------------------------------------------
__global__ __launch_bounds__(256) void attn_kernel(
    const u16* __restrict__ q, const u16* __restrict__ k,
    const u16* __restrict__ vt, u16* __restrict__ ao) {
  __shared__ u16 Ph[4][32][64];
  const int tid = threadIdx.x;
  const int w = tid >> 6, lane = tid & 63;
  const int l15 = lane & 15, l4 = lane >> 4;
  int bid = blockIdx.x;
  int qt = bid & 15, hh = (bid >> 4) & 7, b = bid >> 7;
  int bh_ = b * 8 + hh;
  const size_t base = (size_t)bh_ * 2048 * 64;
  int q0 = qt * 128 + w * 32;

  s16x8 qf[2][2];
#pragma unroll
  for (int mi = 0; mi < 2; ++mi)
#pragma unroll
    for (int ks = 0; ks < 2; ++ks)
      qf[mi][ks] = *(const s16x8*)(q + base + (size_t)(q0 + mi * 16 + l15) * 64 + ks * 32 + l4 * 8);

  const f32x4 fz = {0.f, 0.f, 0.f, 0.f};
  f32x4 O[2][4];
  for (int mi = 0; mi < 2; ++mi)
    for (int nd = 0; nd < 4; ++nd) O[mi][nd] = fz;
  float m_r[2][4], l_r[2][4];
  for (int mi = 0; mi < 2; ++mi)
    for (int rg = 0; rg < 4; ++rg) { m_r[mi][rg] = -3.0e38f; l_r[mi][rg] = 0.f; }

  for (int dt = -1; dt <= 1; ++dt) {
    int kt = qt + dt;
    if (kt < 0 || kt > 15) continue;
    const bool domask = (dt != 0);
    for (int ch = 0; ch < 2; ++ch) {
      int kb = kt * 128 + ch * 64;
      f32x4 S[2][4];
      for (int mi = 0; mi < 2; ++mi)
        for (int nj = 0; nj < 4; ++nj) S[mi][nj] = fz;
#pragma unroll
      for (int nj = 0; nj < 4; ++nj)
#pragma unroll
        for (int ks = 0; ks < 2; ++ks) {
          s16x8 kf = *(const s16x8*)(k + base + (size_t)(kb + nj * 16 + l15) * 64 + ks * 32 + l4 * 8);
#pragma unroll
          for (int mi = 0; mi < 2; ++mi) S[mi][nj] = MFMA16(qf[mi][ks], kf, S[mi][nj]);
        }
      if (domask) {
#pragma unroll
        for (int mi = 0; mi < 2; ++mi)
#pragma unroll
          for (int nj = 0; nj < 4; ++nj)
#pragma unroll
            for (int rg = 0; rg < 4; ++rg) {
              int row = q0 + mi * 16 + l4 * 4 + rg;
              int col = kb + nj * 16 + l15;
              int dd = col - row;
              if (dd > 128 || dd < -128) S[mi][nj][rg] = -1.0e9f;
            }
      }
#pragma unroll
      for (int mi = 0; mi < 2; ++mi)
#pragma unroll
        for (int rg = 0; rg < 4; ++rg) {
          float pm = fmaxf(fmaxf(S[mi][0][rg], S[mi][1][rg]), fmaxf(S[mi][2][rg], S[mi][3][rg]));
          pm = fmaxf(pm, __shfl_xor(pm, 1));
          pm = fmaxf(pm, __shfl_xor(pm, 2));
          pm = fmaxf(pm, __shfl_xor(pm, 4));
          pm = fmaxf(pm, __shfl_xor(pm, 8));
          float mnew = fmaxf(m_r[mi][rg], pm);
          float alpha = exp2f(m_r[mi][rg] - mnew);
          m_r[mi][rg] = mnew;
          l_r[mi][rg] *= alpha;
#pragma unroll
          for (int nd = 0; nd < 4; ++nd) O[mi][nd][rg] *= alpha;
        }
#pragma unroll
      for (int mi = 0; mi < 2; ++mi) {
        float rs[4] = {0.f, 0.f, 0.f, 0.f};
#pragma unroll
        for (int nj = 0; nj < 4; ++nj)
#pragma unroll
          for (int rg = 0; rg < 4; ++rg) {
            float p = exp2f(S[mi][nj][rg] - m_r[mi][rg]);
            rs[rg] += p;
            int row = mi * 16 + l4 * 4 + rg;
            int col = nj * 16 + l15;
            int e = (((col >> 3) ^ (row & 7)) << 3) + (col & 7);
            Ph[w][row][e] = f2bf(p);
          }
#pragma unroll
        for (int rg = 0; rg < 4; ++rg) {
          float s = rs[rg];
          s += __shfl_xor(s, 1);
          s += __shfl_xor(s, 2);
          s += __shfl_xor(s, 4);
          s += __shfl_xor(s, 8);
          l_r[mi][rg] += s;
        }
      }
#pragma unroll
      for (int ksp = 0; ksp < 2; ++ksp) {
        s16x8 pa[2];
#pragma unroll
        for (int mi = 0; mi < 2; ++mi) {
          int row = mi * 16 + l15;
          int sl = (ksp * 4 + l4) ^ (row & 7);
          pa[mi] = *(const s16x8*)&Ph[w][row][sl * 8];
        }
#pragma unroll
        for (int nd = 0; nd < 4; ++nd) {
          s16x8 vf = *(const s16x8*)(vt + base + (size_t)(nd * 16 + l15) * 2048 + kb + ksp * 32 + l4 * 8);
#pragma unroll
          for (int mi = 0; mi < 2; ++mi) O[mi][nd] = MFMA16(pa[mi], vf, O[mi][nd]);
        }
      }
    }
  }
#pragma unroll
  for (int mi = 0; mi < 2; ++mi)
#pragma unroll
    for (int rg = 0; rg < 4; ++rg) {
      float inv = 1.0f / l_r[mi][rg];
      int s_g = q0 + mi * 16 + l4 * 4 + rg;
#pragma unroll
      for (int nd = 0; nd < 4; ++nd) {
        float v = O[mi][nd][rg] * inv;
        int c_g = hh * 64 + nd * 16 + l15;
        ao[((size_t)b * 2048 + s_g) * 512 + c_g] = f2bf(v);
      }
    }
}

// ---------------------------------------------------------------------------
extern "C" void kernel_launch(void* const* d_in, const int* in_sizes, int n_in,
                              void* d_out, int out_size, void* d_ws, size_t ws_size,
                              hipStream_t stream) {
  const float* x = (const float*)d_in[0];      // [4,2048,512]
  const float* wqkv = (const float*)d_in[1];   // [512,1536]
  const float* wproj = (const float*)d_in[2];  // [512,512]
  float* out = (float*)d_out;                  // [4,2048,512]

  char* ws = (char*)d_ws;
  size_t off = 0;
  auto alloc = [&](size_t bytes) {
    void* p = ws + off;
    off += (bytes + 255) & ~(size_t)255;
    return p;
  };
  const size_t E = (size_t)4 * 8 * 2048 * 64;  // 4.19M elems
  u16* Xb  = (u16*)alloc(E * 2);
  u16* qb  = (u16*)alloc(E * 2);
  u16* kb  = (u16*)alloc(E * 2);
  u16* vtb = (u16*)alloc(E * 2);
  u16* aob = (u16*)alloc(E * 2);
  u16* wqT = (u16*)alloc((size_t)1536 * 512 * 2);
  u16* wpT = (u16*)alloc((size_t)512 * 512 * 2);

  xcast<<<dim3(2048), dim3(256), 0, stream>>>(x, Xb);
  wcastT<1><<<dim3(384), dim3(256), 0, stream>>>(wqkv, 512, 1536, wqT);
  wcastT<0><<<dim3(128), dim3(256), 0, stream>>>(wproj, 512, 512, wpT);
  gemm_bf16<1><<<dim3(64, 12), dim3(256), 0, stream>>>(Xb, wqT, nullptr, qb, kb, vtb);
  attn_kernel<<<dim3(512), dim3(256), 0, stream>>>(qb, kb, vtb, aob);
  gemm_bf16<0><<<dim3(64, 4), dim3(256), 0, stream>>>(aob, wpT, out, nullptr, nullptr, nullptr);
}